// Round 1
// baseline (901.091 us; speedup 1.0000x reference)
//
#include <hip/hip_runtime.h>

// NonMaximaSuppression2d: out = x * (x > max over 3x3 neighborhood excluding
// center), replicate ("edge") padding. Input fp32 (8,4,2048,2048).
// Clamped-index loads reproduce edge padding exactly (border pixels compare
// against themselves -> output 0, matching the reference).

#define IMG_H 2048
#define IMG_W 2048

__global__ __launch_bounds__(256) void nms2d_kernel(const float* __restrict__ x,
                                                    float* __restrict__ out,
                                                    int nplanes) {
    const int wq = IMG_W / 4;  // float4 groups per row
    long long tid = (long long)blockIdx.x * blockDim.x + threadIdx.x;
    long long total = (long long)nplanes * IMG_H * wq;
    if (tid >= total) return;

    int col4  = (int)(tid % wq);
    long long rest = tid / wq;
    int row   = (int)(rest % IMG_H);
    int plane = (int)(rest / IMG_H);

    const float* p = x   + (size_t)plane * IMG_H * IMG_W;
    float*       o = out + (size_t)plane * IMG_H * IMG_W;

    int c0 = col4 * 4;
    int rm = row > 0          ? row - 1 : 0;
    int rp = row < IMG_H - 1  ? row + 1 : IMG_H - 1;
    int cl = c0 > 0           ? c0 - 1  : 0;
    int cr = c0 + 4 < IMG_W   ? c0 + 4  : IMG_W - 1;

    const float* rowt = p + (size_t)rm  * IMG_W;
    const float* rowm = p + (size_t)row * IMG_W;
    const float* rowb = p + (size_t)rp  * IMG_W;

    float4 t = *(const float4*)(rowt + c0);
    float4 m = *(const float4*)(rowm + c0);
    float4 b = *(const float4*)(rowb + c0);
    float tl = rowt[cl], tr = rowt[cr];
    float ml = rowm[cl], mr = rowm[cr];
    float bl = rowb[cl], br = rowb[cr];

    // horizontal 3-max for top and bottom rows (all taps included)
    float t0 = fmaxf(fmaxf(tl,  t.x), t.y);
    float t1 = fmaxf(fmaxf(t.x, t.y), t.z);
    float t2 = fmaxf(fmaxf(t.y, t.z), t.w);
    float t3 = fmaxf(fmaxf(t.z, t.w), tr);

    float b0 = fmaxf(fmaxf(bl,  b.x), b.y);
    float b1 = fmaxf(fmaxf(b.x, b.y), b.z);
    float b2 = fmaxf(fmaxf(b.y, b.z), b.w);
    float b3 = fmaxf(fmaxf(b.z, b.w), br);

    // middle row: left+right only (center excluded)
    float m0 = fmaxf(ml,  m.y);
    float m1 = fmaxf(m.x, m.z);
    float m2 = fmaxf(m.y, m.w);
    float m3 = fmaxf(m.z, mr);

    float x0 = fmaxf(fmaxf(t0, b0), m0);
    float x1 = fmaxf(fmaxf(t1, b1), m1);
    float x2 = fmaxf(fmaxf(t2, b2), m2);
    float x3 = fmaxf(fmaxf(t3, b3), m3);

    float4 r;
    r.x = (m.x > x0) ? m.x : 0.0f;
    r.y = (m.y > x1) ? m.y : 0.0f;
    r.z = (m.z > x2) ? m.z : 0.0f;
    r.w = (m.w > x3) ? m.w : 0.0f;

    *(float4*)(o + (size_t)row * IMG_W + c0) = r;
}

extern "C" void kernel_launch(void* const* d_in, const int* in_sizes, int n_in,
                              void* d_out, int out_size, void* d_ws, size_t ws_size,
                              hipStream_t stream) {
    const float* x = (const float*)d_in[0];
    float* out = (float*)d_out;
    int nplanes = in_sizes[0] / (IMG_H * IMG_W);  // 8*4 = 32

    long long total = (long long)nplanes * IMG_H * (IMG_W / 4);
    int blocks = (int)((total + 255) / 256);
    nms2d_kernel<<<blocks, 256, 0, stream>>>(x, out, nplanes);
}